// Round 10
// baseline (424.193 us; speedup 1.0000x reference)
//
#include <hip/hip_runtime.h>
#include <math.h>

#define NB 256      // batch / time steps
#define NV 100      // visits
#define NC 40       // codes per visit
#define NE 128      // embed dim (LSTM "batch")
#define NH 100      // hidden (== feat)
#define NG 400      // 4*NH

// ws layout (float elements)
#define OFF_PRE   0
#define N_PRE     (NB*NE*NG)                 // 13,107,200
#define OFF_TRUH  (OFF_PRE + N_PRE)
#define N_TRUH    (NB*NE)                    // 32,768
#define OFF_LAST  (OFF_TRUH + N_TRUH)        // 256 ints

// ---------------------------------------------------------------- kernel 1
// Fused embed + pregemm. 256 blocks x 512 threads, t = blockIdx.x, one
// block per CU, full-chip in a single round.
//
// R10 vs R9: Bs LDS staging DELETED. B comes straight from L2 as
// float4-over-k (Wih[j*100+k] is k-contiguous), wave-uniform per tn ->
// 3-4 VMEM/thread per 4 k's. Column map: thread owns cols
// {tn*4, 128+tn*4, 256+tn*4} (384 cols, each exactly once -> no wasted
// FMAs, was 28% waste) + {384+tn*4} for tn<4 (== whole wave 0: uniform
// branch). B regs loaded in two halves {grp0,1}/{grp2,3} to keep VGPR
// ~185 < 256 (R3 lesson: >200 live floats -> forced AGPR copies).
// Removes 3200/CU ds_read_b128, 2 barriers, 25.6K-elem staging x2.
// Every output: single ascending-k fmaf chain + (bih+bhh) at store ->
// bit-identical to R9 (absmax 0).
__global__ __launch_bounds__(512, 2) void k_embgemm(
    const int* __restrict__ diag, const float* __restrict__ mask,
    const float* __restrict__ table, const float* __restrict__ Wih,
    const float* __restrict__ bih, const float* __restrict__ bhh,
    float* __restrict__ pre, int* __restrict__ last) {
  __shared__ __align__(16) float As[100][132];   // [k][m], 128 + 4 pad (52.8K)
  __shared__ int lastred[4];

  const int tid = threadIdx.x;
  const int t   = blockIdx.x;                    // 0..255 == batch row
  const int e   = tid & 127;
  const int sub = tid >> 7;                      // 0..3

  // ---- embed b==t straight into As (R9 code, verified bit-exact).
  // fl = i*512 + tid; v = fl>>7, e = fl&127. As[k][m] == x2[t*128+m][k].
  int vmax = -1;
  for (int i = 0; i < 25; ++i) {
    int fl = i * 512 + tid;
    int v  = fl >> 7;                            // 0..99
    const float4* mrow4 = (const float4*)(mask + (t * NV + v) * NC);
    const int4*   drow4 = (const int4*)(diag + (t * NV + v) * NC);
    float acc = 0.f, msum = 0.f;
    #pragma unroll
    for (int cc = 0; cc < 10; ++cc) {            // 40 codes as 10 x (f4,i4)
      float4 mm = mrow4[cc];
      int4   ii = drow4[cc];
      acc = fmaf(mm.x, table[ii.x * NE + e], acc); msum += mm.x;
      acc = fmaf(mm.y, table[ii.y * NE + e], acc); msum += mm.y;
      acc = fmaf(mm.z, table[ii.z * NE + e], acc); msum += mm.z;
      acc = fmaf(mm.w, table[ii.w * NE + e], acc); msum += mm.w;
    }
    int m = fl / 100, k = fl - m * 100;
    As[k][m] = acc;
    if (e == 0 && msum > 0.f) vmax = max(vmax, v);
  }
  if (e == 0) lastred[sub] = vmax;               // sub covers v%4==sub
  __syncthreads();                               // As + lastred ready
  if (tid == 0) {
    int l = max(max(lastred[0], lastred[1]), max(lastred[2], lastred[3]));
    last[t] = max(l, 0);
  }

  // ---- GEMM: rows {tm*4+r, 64+tm*4+r}; cols j0/j1/j2 (+j3 on wave 0).
  const int tm = tid & 15, tn = tid >> 4;        // tn 0..31
  const int j0 = tn * 4, j1 = 128 + j0, j2 = 256 + j0, j3 = 384 + j0;
  const bool has3 = (tn < 4);                    // exactly wave 0 -> uniform
  float acc0[8][4] = {}, acc1[8][4] = {}, acc2[8][4] = {}, acc3[8][4] = {};
  float4 bA[4], bB[4];                           // B-regs, reused per half

  #define ROWUPD(ACC, AX, B, COMP, R)                                     \
    ACC[R][0] = fmaf(AX, B[0].COMP, ACC[R][0]);                           \
    ACC[R][1] = fmaf(AX, B[1].COMP, ACC[R][1]);                           \
    ACC[R][2] = fmaf(AX, B[2].COMP, ACC[R][2]);                           \
    ACC[R][3] = fmaf(AX, B[3].COMP, ACC[R][3]);
  #define GRP8(ACC, B, COMP)                                              \
    ROWUPD(ACC, a0.x, B, COMP, 0) ROWUPD(ACC, a0.y, B, COMP, 1)           \
    ROWUPD(ACC, a0.z, B, COMP, 2) ROWUPD(ACC, a0.w, B, COMP, 3)           \
    ROWUPD(ACC, a1.x, B, COMP, 4) ROWUPD(ACC, a1.y, B, COMP, 5)           \
    ROWUPD(ACC, a1.z, B, COMP, 6) ROWUPD(ACC, a1.w, B, COMP, 7)
  // one k, both accs of the current half (X/Y name the acc pair)
  #define KSTEP2(KOFF, COMP, ACCX, ACCY, GUARDY)                          \
    { float4 a0 = *(const float4*)&As[k4 + KOFF][tm * 4];                 \
      float4 a1 = *(const float4*)&As[k4 + KOFF][64 + tm * 4];            \
      GRP8(ACCX, bA, COMP)                                                \
      if (GUARDY) { GRP8(ACCY, bB, COMP) } }

  for (int k4 = 0; k4 < 100; k4 += 4) {
    // half 1: col groups 0 (acc0) and 1 (acc1)
    #pragma unroll
    for (int c = 0; c < 4; ++c) {
      bA[c] = *(const float4*)&Wih[(j0 + c) * 100 + k4];
      bB[c] = *(const float4*)&Wih[(j1 + c) * 100 + k4];
    }
    KSTEP2(0, x, acc0, acc1, true) KSTEP2(1, y, acc0, acc1, true)
    KSTEP2(2, z, acc0, acc1, true) KSTEP2(3, w, acc0, acc1, true)
    // half 2: col groups 2 (acc2) and 3 (acc3, wave 0 only)
    #pragma unroll
    for (int c = 0; c < 4; ++c)
      bA[c] = *(const float4*)&Wih[(j2 + c) * 100 + k4];
    if (has3) {
      #pragma unroll
      for (int c = 0; c < 4; ++c)
        bB[c] = *(const float4*)&Wih[(j3 + c) * 100 + k4];
    }
    KSTEP2(0, x, acc2, acc3, has3) KSTEP2(1, y, acc2, acc3, has3)
    KSTEP2(2, z, acc2, acc3, has3) KSTEP2(3, w, acc2, acc3, has3)
  }
  #undef KSTEP2
  #undef GRP8
  #undef ROWUPD

  // ---- stores: bias (bih+bhh, same pre-sum as before) added at store.
  float bv0[4], bv1[4], bv2[4], bv3[4] = {};
  #pragma unroll
  for (int c = 0; c < 4; ++c) {
    bv0[c] = bih[j0 + c] + bhh[j0 + c];
    bv1[c] = bih[j1 + c] + bhh[j1 + c];
    bv2[c] = bih[j2 + c] + bhh[j2 + c];
  }
  if (has3) {
    #pragma unroll
    for (int c = 0; c < 4; ++c) bv3[c] = bih[j3 + c] + bhh[j3 + c];
  }
  #pragma unroll
  for (int r = 0; r < 8; ++r) {
    int m = t * 128 + ((r < 4) ? (tm * 4 + r) : (64 + tm * 4 + (r - 4)));
    float* prow = pre + m * NG;
    float4 s;
    s.x = acc0[r][0] + bv0[0]; s.y = acc0[r][1] + bv0[1];
    s.z = acc0[r][2] + bv0[2]; s.w = acc0[r][3] + bv0[3];
    *(float4*)&prow[j0] = s;
    s.x = acc1[r][0] + bv1[0]; s.y = acc1[r][1] + bv1[1];
    s.z = acc1[r][2] + bv1[2]; s.w = acc1[r][3] + bv1[3];
    *(float4*)&prow[j1] = s;
    s.x = acc2[r][0] + bv2[0]; s.y = acc2[r][1] + bv2[1];
    s.z = acc2[r][2] + bv2[2]; s.w = acc2[r][3] + bv2[3];
    *(float4*)&prow[j2] = s;
    if (has3) {
      s.x = acc3[r][0] + bv3[0]; s.y = acc3[r][1] + bv3[1];
      s.z = acc3[r][2] + bv3[2]; s.w = acc3[r][3] + bv3[3];
      *(float4*)&prow[j3] = s;
    }
  }
}

// ---------------------------------------------------------------- kernel 2
// sequential LSTM: 128 blocks (one per e-row), 512 threads. The
// harness-verified 220us structure. R1-R4: fewer waves / fewer LDS
// instrs always lost — 200 weight floats + working set exceeds the 256
// arch-VGPR ceiling, forcing AGPR copies at 1 wave/SIMD. Step floor:
// LDS broadcast pipe (175 x b128 ~= 1645cyc) + update/barriers (~415).
__device__ __forceinline__ float fast_sigmoid(float x) {
  return 1.f / (1.f + __expf(-x));
}
__device__ __forceinline__ float fast_tanh(float x) {
  float ax = fabsf(x);
  float e  = __expf(-2.f * ax);
  float t  = (1.f - e) / (1.f + e);
  return x < 0.f ? -t : t;
}

#define FMA4(A, W, H)                                                     \
  A = fmaf((H).x, (W).x, A); A = fmaf((H).y, (W).y, A);                   \
  A = fmaf((H).z, (W).z, A); A = fmaf((H).w, (W).w, A)

__global__ __launch_bounds__(512, 2) void k_lstm(
    const float* __restrict__ pre, const float* __restrict__ Whh,
    const int* __restrict__ last, float* __restrict__ truh) {
  __shared__ __align__(16) float h_s[100];
  __shared__ float g_s[NG];
  __shared__ int   last_s[NB];
  const int e = blockIdx.x;         // 0..127
  const int j = threadIdx.x;        // active < 400

  // 25 named float4 = 100 weight VGPRs. Whh row stride 400 B -> 16B aligned.
  float4 w00, w01, w02, w03, w04, w05, w06, w07, w08, w09, w10, w11, w12,
         w13, w14, w15, w16, w17, w18, w19, w20, w21, w22, w23, w24;
  if (j < NG) {
    const float4* wr = (const float4*)(Whh + j * 100);
    w00 = wr[0];  w01 = wr[1];  w02 = wr[2];  w03 = wr[3];  w04 = wr[4];
    w05 = wr[5];  w06 = wr[6];  w07 = wr[7];  w08 = wr[8];  w09 = wr[9];
    w10 = wr[10]; w11 = wr[11]; w12 = wr[12]; w13 = wr[13]; w14 = wr[14];
    w15 = wr[15]; w16 = wr[16]; w17 = wr[17]; w18 = wr[18]; w19 = wr[19];
    w20 = wr[20]; w21 = wr[21]; w22 = wr[22]; w23 = wr[23]; w24 = wr[24];
  }
  if (j < NH) h_s[j] = 0.f;
  if (j < NB) last_s[j] = last[j];  // stage once; avoids per-step global read
  float c = 0.f;                    // cell state for thread j<100

  const float* pbase = pre + e * NG + j;        // + t*51200 per step
  float p0 = (j < NG) ? pbase[0]         : 0.f;
  float p1 = (j < NG) ? pbase[51200]     : 0.f;
  float p2 = (j < NG) ? pbase[2 * 51200] : 0.f;
  __syncthreads();

  for (int t = 0; t < NB; ++t) {
    float p3 = (j < NG && t + 3 < NB) ? pbase[(t + 3) * 51200] : 0.f;

    if (j < NG) {
      // 4 independent accumulator chains; h broadcast from LDS via b128.
      float a0 = p0, a1 = 0.f, a2 = 0.f, a3 = 0.f;
      const float4* h4 = (const float4*)h_s;
      float4 h;
      h = h4[0];  FMA4(a0, w00, h);
      h = h4[1];  FMA4(a1, w01, h);
      h = h4[2];  FMA4(a2, w02, h);
      h = h4[3];  FMA4(a3, w03, h);
      h = h4[4];  FMA4(a0, w04, h);
      h = h4[5];  FMA4(a1, w05, h);
      h = h4[6];  FMA4(a2, w06, h);
      h = h4[7];  FMA4(a3, w07, h);
      h = h4[8];  FMA4(a0, w08, h);
      h = h4[9];  FMA4(a1, w09, h);
      h = h4[10]; FMA4(a2, w10, h);
      h = h4[11]; FMA4(a3, w11, h);
      h = h4[12]; FMA4(a0, w12, h);
      h = h4[13]; FMA4(a1, w13, h);
      h = h4[14]; FMA4(a2, w14, h);
      h = h4[15]; FMA4(a3, w15, h);
      h = h4[16]; FMA4(a0, w16, h);
      h = h4[17]; FMA4(a1, w17, h);
      h = h4[18]; FMA4(a2, w18, h);
      h = h4[19]; FMA4(a3, w19, h);
      h = h4[20]; FMA4(a0, w20, h);
      h = h4[21]; FMA4(a1, w21, h);
      h = h4[22]; FMA4(a2, w22, h);
      h = h4[23]; FMA4(a3, w23, h);
      h = h4[24]; FMA4(a0, w24, h);
      float acc = (a0 + a1) + (a2 + a3);
      float act = (j >= 200 && j < 300) ? fast_tanh(acc) : fast_sigmoid(acc);
      g_s[j] = act;
    }
    __syncthreads();                            // gates visible

    if (j < NH) {
      float ig = g_s[j], fg = g_s[100 + j], gg = g_s[200 + j], og = g_s[300 + j];
      c = fmaf(fg, c, ig * gg);
      float h = og * fast_tanh(c);
      h_s[j] = h;
      if (j == last_s[t]) truh[t * NE + e] = h; // hs[b=t, e, last[t]]
    }
    __syncthreads();                            // h_s(t) visible for step t+1

    p0 = p1; p1 = p2; p2 = p3;
  }
}

// ---------------------------------------------------------------- kernel 3
// out[b] = sigmoid( truh[b,:] . fc_w + fc_b )
__global__ __launch_bounds__(128) void k_fc(
    const float* __restrict__ truh, const float* __restrict__ fcw,
    const float* __restrict__ fcb, float* __restrict__ out) {
  int b = blockIdx.x, t = threadIdx.x;
  float v = truh[b * NE + t] * fcw[t];
  #pragma unroll
  for (int o = 32; o > 0; o >>= 1) v += __shfl_down(v, o);
  __shared__ float s[2];
  if ((t & 63) == 0) s[t >> 6] = v;
  __syncthreads();
  if (t == 0) {
    float sum = s[0] + s[1] + fcb[0];
    out[b] = 1.f / (1.f + __expf(-sum));
  }
}

// ---------------------------------------------------------------- launch
extern "C" void kernel_launch(void* const* d_in, const int* in_sizes, int n_in,
                              void* d_out, int out_size, void* d_ws, size_t ws_size,
                              hipStream_t stream) {
  (void)in_sizes; (void)n_in; (void)out_size; (void)ws_size;
  const int*   diag  = (const int*)d_in[0];
  const float* mask  = (const float*)d_in[1];
  const float* table = (const float*)d_in[2];
  const float* Wih   = (const float*)d_in[3];
  const float* Whh   = (const float*)d_in[4];
  const float* bih   = (const float*)d_in[5];
  const float* bhh   = (const float*)d_in[6];
  const float* fcw   = (const float*)d_in[7];
  const float* fcb   = (const float*)d_in[8];

  float* ws   = (float*)d_ws;
  float* pre  = ws + OFF_PRE;
  float* truh = ws + OFF_TRUH;
  int*   last = (int*)(ws + OFF_LAST);
  float* out  = (float*)d_out;

  k_embgemm<<<dim3(NB),  dim3(512), 0, stream>>>(
      diag, mask, table, Wih, bih, bhh, pre, last);
  k_lstm   <<<dim3(NE),  dim3(512), 0, stream>>>(pre, Whh, last, truh);
  k_fc     <<<dim3(NB),  dim3(128), 0, stream>>>(truh, fcw, fcb, out);
}

// Round 11
// 373.080 us; speedup vs baseline: 1.1370x; 1.1370x over previous
//
#include <hip/hip_runtime.h>
#include <math.h>

#define NB 256      // batch / time steps
#define NV 100      // visits
#define NC 40       // codes per visit
#define NE 128      // embed dim (LSTM "batch")
#define NH 100      // hidden (== feat)
#define NG 400      // 4*NH

// ws layout (float elements)
#define OFF_PRE   0
#define N_PRE     (NB*NE*NG)                 // 13,107,200
#define OFF_TRUH  (OFF_PRE + N_PRE)
#define N_TRUH    (NB*NE)                    // 32,768
#define OFF_LAST  (OFF_TRUH + N_TRUH)        // 256 ints

// ---------------------------------------------------------------- kernel 1
// Fused embed + pregemm. 256 blocks x 512 threads, t = blockIdx.x, one
// block per CU.
//
// R11 = R9 (378us best, staged-Bs GEMM) + slim chunk 2. R10's
// global-B experiment regressed 46us (B loads are NOT wave-uniform: tn
// spans 4 values/wave -> 16 vector loads/k4 at L2 latency, 1 wave/SIMD
// occupancy can't hide it) — reverted. Chunk 2 now stages exactly 144
// cols (was 256 with 112 zeros) and computes 8x4 tiles (cols 256..383)
// on all threads + cols 384..399 on wave 0 only (uniform tn<4 branch,
// R10-verified pattern). Per-CU chunk-2 ds_read_b128: 3200 -> 2500;
// staging -11200 elems; zero wasted FMAs. Chains unchanged -> bit-exact.
__global__ __launch_bounds__(512, 2) void k_embgemm(
    const int* __restrict__ diag, const float* __restrict__ mask,
    const float* __restrict__ table, const float* __restrict__ Wih,
    const float* __restrict__ bih, const float* __restrict__ bhh,
    float* __restrict__ pre, int* __restrict__ last) {
  __shared__ __align__(16) float As[100][132];   // [k][m], 128 + 4 pad (52.8K)
  __shared__ __align__(16) float Bs[100][264];   // [k][n], 256 + 8 pad (105.6K)
  __shared__ __align__(16) float bias_s[256];
  __shared__ int lastred[4];

  const int tid = threadIdx.x;
  const int t   = blockIdx.x;                    // 0..255 == batch row
  const int e   = tid & 127;
  const int sub = tid >> 7;                      // 0..3

  // ---- embed b==t straight into As (R9 code, verified bit-exact).
  // fl = i*512 + tid; v = fl>>7, e = fl&127. As[k][m] == x2[t*128+m][k].
  int vmax = -1;
  for (int i = 0; i < 25; ++i) {
    int fl = i * 512 + tid;
    int v  = fl >> 7;                            // 0..99
    const float4* mrow4 = (const float4*)(mask + (t * NV + v) * NC);
    const int4*   drow4 = (const int4*)(diag + (t * NV + v) * NC);
    float acc = 0.f, msum = 0.f;
    #pragma unroll
    for (int cc = 0; cc < 10; ++cc) {            // 40 codes as 10 x (f4,i4)
      float4 mm = mrow4[cc];
      int4   ii = drow4[cc];
      acc = fmaf(mm.x, table[ii.x * NE + e], acc); msum += mm.x;
      acc = fmaf(mm.y, table[ii.y * NE + e], acc); msum += mm.y;
      acc = fmaf(mm.z, table[ii.z * NE + e], acc); msum += mm.z;
      acc = fmaf(mm.w, table[ii.w * NE + e], acc); msum += mm.w;
    }
    int m = fl / 100, k = fl - m * 100;
    As[k][m] = acc;
    if (e == 0 && msum > 0.f) vmax = max(vmax, v);
  }
  if (e == 0) lastred[sub] = vmax;               // sub covers v%4==sub
  __syncthreads();                               // As + lastred ready
  if (tid == 0) {
    int l = max(max(lastred[0], lastred[1]), max(lastred[2], lastred[3]));
    last[t] = max(l, 0);
  }

  const int tm = tid & 15, tn = tid >> 4;        // 16 x 32 thread grid

  #define PG_ROW(ACC, R, AX, BV)                                          \
    ACC[R][0] = fmaf(AX, BV.x, ACC[R][0]);                                \
    ACC[R][1] = fmaf(AX, BV.y, ACC[R][1]);                                \
    ACC[R][2] = fmaf(AX, BV.z, ACC[R][2]);                                \
    ACC[R][3] = fmaf(AX, BV.w, ACC[R][3]);
  #define GRP8(ACC, BV)                                                   \
    PG_ROW(ACC, 0, a0.x, BV) PG_ROW(ACC, 1, a0.y, BV)                     \
    PG_ROW(ACC, 2, a0.z, BV) PG_ROW(ACC, 3, a0.w, BV)                     \
    PG_ROW(ACC, 4, a1.x, BV) PG_ROW(ACC, 5, a1.y, BV)                     \
    PG_ROW(ACC, 6, a1.z, BV) PG_ROW(ACC, 7, a1.w, BV)

  // ================= chunk 1: cols 0..255 (full 8x8) =================
  {
    for (int idx = tid; idx < 25600; idx += 512) {
      int n = idx / 100, k = idx - n * 100;
      Bs[k][n] = Wih[n * 100 + k];               // coalesced along k
    }
    if (tid < 256) bias_s[tid] = bih[tid] + bhh[tid];
    __syncthreads();

    float acc0[8][4] = {}, acc1[8][4] = {};
    for (int k = 0; k < 100; ++k) {
      float4 a0 = *(const float4*)&As[k][tm * 4];        // 2-way, free
      float4 a1 = *(const float4*)&As[k][64 + tm * 4];   // 2-way, free
      float4 b0 = *(const float4*)&Bs[k][tn * 4];        // broadcast
      float4 b1 = *(const float4*)&Bs[k][128 + tn * 4];  // broadcast
      GRP8(acc0, b0)
      GRP8(acc1, b1)
    }
    const int j0 = tn * 4, j1 = 128 + tn * 4;
    float4 bv0 = *(const float4*)&bias_s[j0];
    float4 bv1 = *(const float4*)&bias_s[j1];
    #pragma unroll
    for (int r = 0; r < 8; ++r) {
      int m = t * 128 + ((r < 4) ? (tm * 4 + r) : (64 + tm * 4 + (r - 4)));
      float* prow = pre + m * NG;
      float4 s;
      s.x = acc0[r][0] + bv0.x; s.y = acc0[r][1] + bv0.y;
      s.z = acc0[r][2] + bv0.z; s.w = acc0[r][3] + bv0.w;
      *(float4*)&prow[j0] = s;
      s.x = acc1[r][0] + bv1.x; s.y = acc1[r][1] + bv1.y;
      s.z = acc1[r][2] + bv1.z; s.w = acc1[r][3] + bv1.w;
      *(float4*)&prow[j1] = s;
    }
    __syncthreads();                             // Bs safe to overwrite
  }

  // ========== chunk 2: cols 256..399 (144 real, zero waste) ==========
  {
    for (int idx = tid; idx < 14400; idx += 512) {
      int n = idx / 100, k = idx - n * 100;      // n 0..143
      Bs[k][n] = Wih[(256 + n) * 100 + k];       // coalesced along k
    }
    if (tid < 144) bias_s[tid] = bih[256 + tid] + bhh[256 + tid];
    __syncthreads();

    const bool has3 = (tn < 4);                  // wave 0 only: uniform
    float acc0[8][4] = {}, acc1[8][4] = {};
    for (int k = 0; k < 100; ++k) {
      float4 a0 = *(const float4*)&As[k][tm * 4];
      float4 a1 = *(const float4*)&As[k][64 + tm * 4];
      float4 b0 = *(const float4*)&Bs[k][tn * 4];        // cols 256+tn*4
      GRP8(acc0, b0)
      if (has3) {
        float4 b1 = *(const float4*)&Bs[k][128 + tn * 4]; // cols 384..399
        GRP8(acc1, b1)
      }
    }
    const int j0 = 256 + tn * 4, j1 = 384 + tn * 4;
    float4 bv0 = *(const float4*)&bias_s[tn * 4];
    float4 bv1 = has3 ? *(const float4*)&bias_s[128 + tn * 4]
                      : make_float4(0.f, 0.f, 0.f, 0.f);
    #pragma unroll
    for (int r = 0; r < 8; ++r) {
      int m = t * 128 + ((r < 4) ? (tm * 4 + r) : (64 + tm * 4 + (r - 4)));
      float* prow = pre + m * NG;
      float4 s;
      s.x = acc0[r][0] + bv0.x; s.y = acc0[r][1] + bv0.y;
      s.z = acc0[r][2] + bv0.z; s.w = acc0[r][3] + bv0.w;
      *(float4*)&prow[j0] = s;
      if (has3) {
        s.x = acc1[r][0] + bv1.x; s.y = acc1[r][1] + bv1.y;
        s.z = acc1[r][2] + bv1.z; s.w = acc1[r][3] + bv1.w;
        *(float4*)&prow[j1] = s;
      }
    }
  }
  #undef GRP8
  #undef PG_ROW
}

// ---------------------------------------------------------------- kernel 2
// sequential LSTM: 128 blocks (one per e-row), 512 threads. The
// harness-verified 220us structure. R1-R4: fewer waves / fewer LDS
// instrs always lost — 200 weight floats + working set exceeds the
// arch-VGPR budget, forcing AGPR copies at 1 wave/SIMD. Step floor:
// LDS broadcast pipe (175 x b128 ~= 1645cyc) + update/barriers (~415).
__device__ __forceinline__ float fast_sigmoid(float x) {
  return 1.f / (1.f + __expf(-x));
}
__device__ __forceinline__ float fast_tanh(float x) {
  float ax = fabsf(x);
  float e  = __expf(-2.f * ax);
  float t  = (1.f - e) / (1.f + e);
  return x < 0.f ? -t : t;
}

#define FMA4(A, W, H)                                                     \
  A = fmaf((H).x, (W).x, A); A = fmaf((H).y, (W).y, A);                   \
  A = fmaf((H).z, (W).z, A); A = fmaf((H).w, (W).w, A)

__global__ __launch_bounds__(512, 2) void k_lstm(
    const float* __restrict__ pre, const float* __restrict__ Whh,
    const int* __restrict__ last, float* __restrict__ truh) {
  __shared__ __align__(16) float h_s[100];
  __shared__ float g_s[NG];
  __shared__ int   last_s[NB];
  const int e = blockIdx.x;         // 0..127
  const int j = threadIdx.x;        // active < 400

  // 25 named float4 = 100 weight VGPRs. Whh row stride 400 B -> 16B aligned.
  float4 w00, w01, w02, w03, w04, w05, w06, w07, w08, w09, w10, w11, w12,
         w13, w14, w15, w16, w17, w18, w19, w20, w21, w22, w23, w24;
  if (j < NG) {
    const float4* wr = (const float4*)(Whh + j * 100);
    w00 = wr[0];  w01 = wr[1];  w02 = wr[2];  w03 = wr[3];  w04 = wr[4];
    w05 = wr[5];  w06 = wr[6];  w07 = wr[7];  w08 = wr[8];  w09 = wr[9];
    w10 = wr[10]; w11 = wr[11]; w12 = wr[12]; w13 = wr[13]; w14 = wr[14];
    w15 = wr[15]; w16 = wr[16]; w17 = wr[17]; w18 = wr[18]; w19 = wr[19];
    w20 = wr[20]; w21 = wr[21]; w22 = wr[22]; w23 = wr[23]; w24 = wr[24];
  }
  if (j < NH) h_s[j] = 0.f;
  if (j < NB) last_s[j] = last[j];  // stage once; avoids per-step global read
  float c = 0.f;                    // cell state for thread j<100

  const float* pbase = pre + e * NG + j;        // + t*51200 per step
  float p0 = (j < NG) ? pbase[0]         : 0.f;
  float p1 = (j < NG) ? pbase[51200]     : 0.f;
  float p2 = (j < NG) ? pbase[2 * 51200] : 0.f;
  __syncthreads();

  for (int t = 0; t < NB; ++t) {
    float p3 = (j < NG && t + 3 < NB) ? pbase[(t + 3) * 51200] : 0.f;

    if (j < NG) {
      // 4 independent accumulator chains; h broadcast from LDS via b128.
      float a0 = p0, a1 = 0.f, a2 = 0.f, a3 = 0.f;
      const float4* h4 = (const float4*)h_s;
      float4 h;
      h = h4[0];  FMA4(a0, w00, h);
      h = h4[1];  FMA4(a1, w01, h);
      h = h4[2];  FMA4(a2, w02, h);
      h = h4[3];  FMA4(a3, w03, h);
      h = h4[4];  FMA4(a0, w04, h);
      h = h4[5];  FMA4(a1, w05, h);
      h = h4[6];  FMA4(a2, w06, h);
      h = h4[7];  FMA4(a3, w07, h);
      h = h4[8];  FMA4(a0, w08, h);
      h = h4[9];  FMA4(a1, w09, h);
      h = h4[10]; FMA4(a2, w10, h);
      h = h4[11]; FMA4(a3, w11, h);
      h = h4[12]; FMA4(a0, w12, h);
      h = h4[13]; FMA4(a1, w13, h);
      h = h4[14]; FMA4(a2, w14, h);
      h = h4[15]; FMA4(a3, w15, h);
      h = h4[16]; FMA4(a0, w16, h);
      h = h4[17]; FMA4(a1, w17, h);
      h = h4[18]; FMA4(a2, w18, h);
      h = h4[19]; FMA4(a3, w19, h);
      h = h4[20]; FMA4(a0, w20, h);
      h = h4[21]; FMA4(a1, w21, h);
      h = h4[22]; FMA4(a2, w22, h);
      h = h4[23]; FMA4(a3, w23, h);
      h = h4[24]; FMA4(a0, w24, h);
      float acc = (a0 + a1) + (a2 + a3);
      float act = (j >= 200 && j < 300) ? fast_tanh(acc) : fast_sigmoid(acc);
      g_s[j] = act;
    }
    __syncthreads();                            // gates visible

    if (j < NH) {
      float ig = g_s[j], fg = g_s[100 + j], gg = g_s[200 + j], og = g_s[300 + j];
      c = fmaf(fg, c, ig * gg);
      float h = og * fast_tanh(c);
      h_s[j] = h;
      if (j == last_s[t]) truh[t * NE + e] = h; // hs[b=t, e, last[t]]
    }
    __syncthreads();                            // h_s(t) visible for step t+1

    p0 = p1; p1 = p2; p2 = p3;
  }
}

// ---------------------------------------------------------------- kernel 3
// out[b] = sigmoid( truh[b,:] . fc_w + fc_b )
__global__ __launch_bounds__(128) void k_fc(
    const float* __restrict__ truh, const float* __restrict__ fcw,
    const float* __restrict__ fcb, float* __restrict__ out) {
  int b = blockIdx.x, t = threadIdx.x;
  float v = truh[b * NE + t] * fcw[t];
  #pragma unroll
  for (int o = 32; o > 0; o >>= 1) v += __shfl_down(v, o);
  __shared__ float s[2];
  if ((t & 63) == 0) s[t >> 6] = v;
  __syncthreads();
  if (t == 0) {
    float sum = s[0] + s[1] + fcb[0];
    out[b] = 1.f / (1.f + __expf(-sum));
  }
}

// ---------------------------------------------------------------- launch
extern "C" void kernel_launch(void* const* d_in, const int* in_sizes, int n_in,
                              void* d_out, int out_size, void* d_ws, size_t ws_size,
                              hipStream_t stream) {
  (void)in_sizes; (void)n_in; (void)out_size; (void)ws_size;
  const int*   diag  = (const int*)d_in[0];
  const float* mask  = (const float*)d_in[1];
  const float* table = (const float*)d_in[2];
  const float* Wih   = (const float*)d_in[3];
  const float* Whh   = (const float*)d_in[4];
  const float* bih   = (const float*)d_in[5];
  const float* bhh   = (const float*)d_in[6];
  const float* fcw   = (const float*)d_in[7];
  const float* fcb   = (const float*)d_in[8];

  float* ws   = (float*)d_ws;
  float* pre  = ws + OFF_PRE;
  float* truh = ws + OFF_TRUH;
  int*   last = (int*)(ws + OFF_LAST);
  float* out  = (float*)d_out;

  k_embgemm<<<dim3(NB),  dim3(512), 0, stream>>>(
      diag, mask, table, Wih, bih, bhh, pre, last);
  k_lstm   <<<dim3(NE),  dim3(512), 0, stream>>>(pre, Whh, last, truh);
  k_fc     <<<dim3(NB),  dim3(128), 0, stream>>>(truh, fcw, fcb, out);
}